// Round 5
// baseline (711.741 us; speedup 1.0000x reference)
//
#include <hip/hip_runtime.h>

#define N_USER 50000
#define N_REST 20000
#define D_IN   512
#define HID    256
#define E_REV  500000
#define E_NEAR 250000
#define E_TOT  (E_REV + E_NEAR)
#define MU_PAD 50048   // ceil(50000/128)*128
#define MR_PAD 20096   // ceil(20000/128)*128

static inline int ceil_div(int a, int b) { return (a + b - 1) / b; }

typedef _Float16 f16x8 __attribute__((ext_vector_type(8)));
typedef _Float16 f16x4 __attribute__((ext_vector_type(4)));
typedef float    f32x4 __attribute__((ext_vector_type(4)));

typedef const __attribute__((address_space(1))) void* gaddr_t;
typedef __attribute__((address_space(3))) void*       saddr_t;

// ---------------------------------------------------------------------------
// CSR-build bodies, fused as per-block strided chunks inside GEMM blocks.
// ---------------------------------------------------------------------------
struct CFArgs {
    const int *rsrc, *rdst, *nsrc, *ndst;
    int *cnt_ur, *cnt_ru, *cnt_rr, *cnt_ns;
    int *slot_ur, *slot_ru, *slot_rr;
    const int *ptr_ur, *ptr_ru, *ptr_rr;
    int *csr_ur, *csr_ru, *csr_rr;
};

__device__ __forceinline__ void count_edge(const CFArgs& a, int e) {
    if (e < E_REV) {
        int s = a.rsrc[e], d = a.rdst[e];
        a.slot_ur[e] = atomicAdd(&a.cnt_ur[d], 1);
        a.slot_ru[e] = atomicAdd(&a.cnt_ru[s], 1);
    } else {
        int e2 = e - E_REV;
        int s = a.nsrc[e2], d = a.ndst[e2];
        atomicAdd(&a.cnt_ns[s], 1);
        a.slot_rr[e2] = atomicAdd(&a.cnt_rr[d], 1);
    }
}

__device__ __forceinline__ void fill_edge(const CFArgs& a, int e) {
    if (e < E_REV) {
        int s = a.rsrc[e], d = a.rdst[e];
        a.csr_ur[a.ptr_ur[d] + a.slot_ur[e]] = s;
        a.csr_ru[a.ptr_ru[s] + a.slot_ru[e]] = d;
    } else {
        int e2 = e - E_REV;
        a.csr_rr[a.ptr_rr[a.ndst[e2]] + a.slot_rr[e2]] = a.nsrc[e2];
    }
}

// ---------------------------------------------------------------------------
// B-chunk-resident GEMM: C[M,256] = A[M,K] @ Bt[256,K]^T, K = 128*NCH.
// Bs = one 64 KB chunk of B (256 rows x 128 cols f16), XOR slot swizzle.
// A streams global->register, 1-ahead ring; NO barriers inside the MFMA
// sweep; 2 __syncthreads per chunk boundary (3-7 per block total).
// 8 waves = 2M x 4N over a 128x256 tile. f16: launch_bounds(512,4) ->
// ~121 regs, 2 blocks/CU. fp32-A input: (512,2) (ring needs ~150 regs).
// FUSE: 0 none, 1 count chunk, 2 fill chunk (overlaps stage-0 drain).
// ---------------------------------------------------------------------------
struct GJobs {
    const void* A[3];
    const _Float16* Bt[3];
    void* C[3];
    const float* S[3];
    int MB[3];
    int Mreal[3];
};

template<int KT, bool AFP32, bool SCALE, bool OUT16, int FUSE, int MINW>
__global__ __launch_bounds__(512, MINW) void k_gemm(GJobs jb, CFArgs cf, int echunk) {
    __shared__ _Float16 Bs[256][128];   // 64 KB

    int bx = blockIdx.x, z = 0;
    if (bx >= jb.MB[0]) {
        bx -= jb.MB[0]; z = 1;
        if (bx >= jb.MB[1]) { bx -= jb.MB[1]; z = 2; }
    }

    const int M = jb.Mreal[z];
    const _Float16* __restrict__ Bt = jb.Bt[z];
    const float* __restrict__ S = jb.S[z];
    void* __restrict__ Cout = jb.C[z];

    const int tid = threadIdx.x, wave = tid >> 6, lane = tid & 63;
    const int bm = bx * 128;
    const int fr = lane & 15, q = lane >> 4;
    const int wm = wave >> 2, wn = wave & 3;

    // Stage one 128-col B chunk: linear LDS dest (wave-uniform base + lane*16),
    // pre-swizzled global source slot: src = (lane&15) ^ (row&7).
    auto stageB = [&](int c) {
#pragma unroll
        for (int i = 0; i < 8; i++) {
            int rr4 = i * 8 + wave;                  // covers rows rr4*4..rr4*4+3
            int row = rr4 * 4 + (lane >> 4);
            int src = (lane & 15) ^ (row & 7);
            __builtin_amdgcn_global_load_lds(
                (gaddr_t)(Bt + (size_t)row * KT + c * 128 + src * 8),
                (saddr_t)(&Bs[0][0] + rr4 * 512), 16, 0, 0);
        }
    };

    // A row bases (clamped for unpadded fp32 x)
    size_t arow[4];
#pragma unroll
    for (int i = 0; i < 4; i++) {
        int r = bm + wm * 64 + i * 16 + fr;
        if (AFP32) r = (r < M) ? r : (M - 1);
        arow[i] = (size_t)r * KT;
    }
    const float*    Af = AFP32 ? (const float*)jb.A[z] : nullptr;
    const _Float16* Ah = AFP32 ? nullptr : (const _Float16*)jb.A[z];

    f16x8 afr[2][4];
    f32x4 a0r[2][4], a1r[2][4];

    f32x4 acc[4][4];
#pragma unroll
    for (int i = 0; i < 4; i++)
#pragma unroll
        for (int j = 0; j < 4; j++) acc[i][j] = (f32x4){0.f, 0.f, 0.f, 0.f};

#define LOAD_A(s, g)                                                          \
    do {                                                                      \
        int kg = (g) * 32 + q * 8;                                            \
        if (AFP32) {                                                          \
            _Pragma("unroll")                                                 \
            for (int i = 0; i < 4; i++) {                                     \
                a0r[s][i] = *(const f32x4*)(Af + arow[i] + kg);               \
                a1r[s][i] = *(const f32x4*)(Af + arow[i] + kg + 4);           \
            }                                                                 \
        } else {                                                              \
            _Pragma("unroll")                                                 \
            for (int i = 0; i < 4; i++)                                       \
                afr[s][i] = *(const f16x8*)(Ah + arow[i] + kg);               \
        }                                                                     \
    } while (0)

    constexpr int NG  = KT / 32;    // k-steps
    constexpr int NCH = KT / 128;   // B chunks

    stageB(0);
    LOAD_A(0, 0);
    if (FUSE != 0) {
        int e_end = (blockIdx.x + 1) * echunk;
        if (e_end > E_TOT) e_end = E_TOT;
        for (int e = blockIdx.x * echunk + tid; e < e_end; e += 512) {
            if (FUSE == 1) count_edge(cf, e);
            else           fill_edge(cf, e);
        }
    }
    __syncthreads();                 // B chunk 0 staged (drains everything)

#pragma unroll
    for (int c = 0; c < NCH; ++c) {
#pragma unroll
        for (int t = 0; t < 4; ++t) {
            const int g = c * 4 + t;
            if (g + 1 < NG) LOAD_A((g + 1) & 1, g + 1);   // 1-ahead ring
            f16x8 bfv[4];
#pragma unroll
            for (int j = 0; j < 4; j++) {
                int brow = wn * 64 + j * 16 + fr;
                bfv[j] = *(const f16x8*)((const char*)&Bs[0][0] + brow * 256 +
                                         (((t * 4 + q) ^ (brow & 7)) << 4));
            }
#pragma unroll
            for (int i = 0; i < 4; i++) {
                f16x8 av;
                if (AFP32) {
                    f32x4 x0 = a0r[g & 1][i], x1 = a1r[g & 1][i];
                    av = (f16x8){(_Float16)x0[0], (_Float16)x0[1],
                                 (_Float16)x0[2], (_Float16)x0[3],
                                 (_Float16)x1[0], (_Float16)x1[1],
                                 (_Float16)x1[2], (_Float16)x1[3]};
                } else av = afr[g & 1][i];
#pragma unroll
                for (int j = 0; j < 4; j++)
                    acc[i][j] = __builtin_amdgcn_mfma_f32_16x16x32_f16(
                        av, bfv[j], acc[i][j], 0, 0, 0);
            }
        }
        if (c + 1 < NCH) {
            __syncthreads();         // all waves done reading chunk c
            stageB(c + 1);
            __syncthreads();         // chunk c+1 staged
        }
    }
#undef LOAD_A

    // epilogue
#pragma unroll
    for (int i = 0; i < 4; i++) {
        const int row0 = bm + wm * 64 + i * 16 + q * 4;
        float sv[4];
        if (SCALE) {
#pragma unroll
            for (int rr = 0; rr < 4; rr++) sv[rr] = S[row0 + rr];
        }
#pragma unroll
        for (int j = 0; j < 4; j++) {
            const int col = wn * 64 + j * 16 + fr;
#pragma unroll
            for (int rr = 0; rr < 4; rr++) {
                const int gr = row0 + rr;
                float v = acc[i][j][rr];
                if (SCALE) v *= sv[rr];
                if (OUT16) {
                    ((_Float16*)Cout)[(size_t)gr * HID + col] = (_Float16)v;
                } else {
                    if (gr < M) ((float*)Cout)[(size_t)gr * HID + col] = v;
                }
            }
        }
    }
}

// Weight prep: W[K][256] fp32 -> Wt[256][K] f16 (batched over 10 matrices)
struct WJobs { const float* w[10]; _Float16* wt[10]; int K[10]; };
__global__ void wprep(WJobs jb) {
    int m = blockIdx.y;
    const float* w = jb.w[m];
    _Float16* wt = jb.wt[m];
    int K = jb.K[m];
    int o = blockIdx.x * 256 + threadIdx.x;
    if (o >= K * 256) return;
    int n = (K == 512) ? (o >> 9) : (o >> 8);
    int k = o & (K - 1);
    wt[o] = (_Float16)w[(size_t)k * 256 + n];
}

__device__ __forceinline__ float inv_deg(int c, float add) {
    float d = (float)c + add;
    return (d > 0.f) ? rsqrtf(d) : 0.f;
}

// Fused: blocks 0-2 run the 3 exclusive scans; blocks 3+ compute inv degrees.
struct ScanJobs { const int* cnt[3]; int* ptr[3]; int n[3]; };
__global__ __launch_bounds__(1024) void invscan(ScanJobs jb,
        const int* __restrict__ cnt_ru, const int* __restrict__ cnt_ur,
        const int* __restrict__ cnt_ns, const int* __restrict__ cnt_rr,
        float* __restrict__ inv_us, float* __restrict__ inv_rd,
        float* __restrict__ inv_ns, float* __restrict__ inv_nd) {
    if (blockIdx.x >= 3) {
        int i = (blockIdx.x - 3) * 1024 + threadIdx.x;
        if (i < N_USER) inv_us[i] = inv_deg(cnt_ru[i], 0.f);
        if (i < N_REST) {
            inv_rd[i] = inv_deg(cnt_ur[i], 0.f);
            inv_ns[i] = inv_deg(cnt_ns[i], 1.f);
            inv_nd[i] = inv_deg(cnt_rr[i], 1.f);
        }
        return;
    }
    const int* cnt = jb.cnt[blockIdx.x];
    int* ptr = jb.ptr[blockIdx.x];
    const int n = jb.n[blockIdx.x];          // divisible by 4
    __shared__ int wsum[16];
    __shared__ int carry_s;
    const int tid = threadIdx.x, lane = tid & 63, wid = tid >> 6;
    if (tid == 0) carry_s = 0;
    __syncthreads();
    for (int base = 0; base < n; base += 4096) {
        int i0 = base + tid * 4;
        int4 v = make_int4(0, 0, 0, 0);
        if (i0 < n) v = *(const int4*)&cnt[i0];
        int s = v.x + v.y + v.z + v.w;
        int x = s;
#pragma unroll
        for (int off = 1; off < 64; off <<= 1) {
            int y = __shfl_up(x, off, 64);
            if (lane >= off) x += y;
        }
        if (lane == 63) wsum[wid] = x;
        __syncthreads();
        if (wid == 0 && lane < 16) {
            int w = wsum[lane];
#pragma unroll
            for (int off = 1; off < 16; off <<= 1) {
                int y = __shfl_up(w, off, 16);
                if (lane >= off) w += y;
            }
            wsum[lane] = w;
        }
        __syncthreads();
        int wave_off = (wid > 0) ? wsum[wid - 1] : 0;
        if (i0 < n) {
            int e = carry_s + wave_off + (x - s);
            int4 o = make_int4(e, e + v.x, e + v.x + v.y, e + v.x + v.y + v.z);
            *(int4*)&ptr[i0] = o;
        }
        __syncthreads();
        if (tid == 0) carry_s += wsum[15];
        __syncthreads();
    }
    if (threadIdx.x == 0) ptr[n] = carry_s;
}

// ---------------------------------------------------------------------------
// Fused aggregation (unchanged): at the random-gather fabric floor.
// ---------------------------------------------------------------------------
__device__ __forceinline__ void acc_rows16(const int* __restrict__ csr, int beg, int end,
                                           const _Float16* __restrict__ hw, int c, f32x4& acc) {
    int e = beg;
    for (; e + 3 < end; e += 4) {
        int s0 = csr[e], s1 = csr[e + 1], s2 = csr[e + 2], s3 = csr[e + 3];
        f16x4 v0 = *(const f16x4*)&hw[(size_t)s0 * HID + c];
        f16x4 v1 = *(const f16x4*)&hw[(size_t)s1 * HID + c];
        f16x4 v2 = *(const f16x4*)&hw[(size_t)s2 * HID + c];
        f16x4 v3 = *(const f16x4*)&hw[(size_t)s3 * HID + c];
#pragma unroll
        for (int r = 0; r < 4; r++)
            acc[r] += ((float)v0[r] + (float)v1[r]) + ((float)v2[r] + (float)v3[r]);
    }
    for (; e < end; e++) {
        f16x4 v = *(const f16x4*)&hw[(size_t)csr[e] * HID + c];
#pragma unroll
        for (int r = 0; r < 4; r++) acc[r] += (float)v[r];
    }
}

__global__ __launch_bounds__(256) void agg_all(
    const int* __restrict__ ptr_ur, const int* __restrict__ csr_ur, const _Float16* __restrict__ hwu,
    const int* __restrict__ ptr_rr, const int* __restrict__ csr_rr, const _Float16* __restrict__ hwa,
    const int* __restrict__ ptr_ru, const int* __restrict__ csr_ru, const _Float16* __restrict__ hwb,
    const float* __restrict__ inv_rd, const float* __restrict__ inv_nd, const float* __restrict__ inv_us,
    const float* __restrict__ b_ur, const float* __restrict__ b_rr, const float* __restrict__ b_ru,
    _Float16* __restrict__ out_r, _Float16* __restrict__ out_u) {
    int w = (blockIdx.x * blockDim.x + threadIdx.x) >> 6;
    int c = (threadIdx.x & 63) * 4;

    if (w < N_REST) {
        int row = w;
        f32x4 au = (f32x4){0.f, 0.f, 0.f, 0.f};
        acc_rows16(csr_ur, ptr_ur[row], ptr_ur[row + 1], hwu, c, au);

        f32x4 ar;
        {   // self-loop (hwa pre-scaled by inv_ns)
            f16x4 v = *(const f16x4*)&hwa[(size_t)row * HID + c];
#pragma unroll
            for (int r = 0; r < 4; r++) ar[r] = (float)v[r];
        }
        acc_rows16(csr_rr, ptr_rr[row], ptr_rr[row + 1], hwa, c, ar);

        float sd = inv_rd[row], sn = inv_nd[row];
        f32x4 bu = *(const f32x4*)&b_ur[c];
        f32x4 br = *(const f32x4*)&b_rr[c];
        f16x4 oh;
#pragma unroll
        for (int r = 0; r < 4; r++)
            oh[r] = (_Float16)fmaxf(bu[r] + br[r] + sd * au[r] + sn * ar[r], 0.f);
        *(f16x4*)&out_r[(size_t)row * HID + c] = oh;
    } else {
        int row = w - N_REST;
        if (row >= N_USER) return;
        f32x4 a = (f32x4){0.f, 0.f, 0.f, 0.f};
        acc_rows16(csr_ru, ptr_ru[row], ptr_ru[row + 1], hwb, c, a);

        float su = inv_us[row];
        f32x4 b = *(const f32x4*)&b_ru[c];
        f16x4 oh;
#pragma unroll
        for (int r = 0; r < 4; r++)
            oh[r] = (_Float16)fmaxf(b[r] + su * a[r], 0.f);
        *(f16x4*)&out_u[(size_t)row * HID + c] = oh;
    }
}

// ---------------------------------------------------------------------------
extern "C" void kernel_launch(void* const* d_in, const int* in_sizes, int n_in,
                              void* d_out, int out_size, void* d_ws, size_t ws_size,
                              hipStream_t stream) {
    const float* x_user   = (const float*)d_in[0];
    const float* x_rest   = (const float*)d_in[1];
    const int*   rev_src  = (const int*)d_in[2];
    const int*   rev_dst  = (const int*)d_in[3];
    const int*   near_src = (const int*)d_in[4];
    const int*   near_dst = (const int*)d_in[5];
    const float* Win_user = (const float*)d_in[6];
    const float* Win_rest = (const float*)d_in[7];
    const float* W1_ur = (const float*)d_in[8];  const float* b1_ur = (const float*)d_in[9];
    const float* W1_ru = (const float*)d_in[10]; const float* b1_ru = (const float*)d_in[11];
    const float* W1_rr = (const float*)d_in[12]; const float* b1_rr = (const float*)d_in[13];
    const float* W2_ur = (const float*)d_in[14]; const float* b2_ur = (const float*)d_in[15];
    const float* W2_ru = (const float*)d_in[16]; const float* b2_ru = (const float*)d_in[17];
    const float* W2_rr = (const float*)d_in[18]; const float* b2_rr = (const float*)d_in[19];
    const float* Wout_user = (const float*)d_in[20];
    const float* Wout_rest = (const float*)d_in[21];

    // ---- workspace layout ----
    _Float16* p = (_Float16*)d_ws;
    _Float16* h_u = p;                 p += (size_t)MU_PAD * HID;
    _Float16* h_r = p;                 p += (size_t)MR_PAD * HID;
    _Float16* hwu = p;                 p += (size_t)MU_PAD * HID;
    _Float16* hwa = p;                 p += (size_t)MR_PAD * HID;
    _Float16* hwb = p;                 p += (size_t)MR_PAD * HID;
    _Float16* wtin_u = p;              p += 256 * 512;
    _Float16* wtin_r = p;              p += 256 * 512;
    _Float16* wt1ur = p;               p += 256 * 256;
    _Float16* wt1ru = p;               p += 256 * 256;
    _Float16* wt1rr = p;               p += 256 * 256;
    _Float16* wt2ur = p;               p += 256 * 256;
    _Float16* wt2ru = p;               p += 256 * 256;
    _Float16* wt2rr = p;               p += 256 * 256;
    _Float16* wtout_u = p;             p += 256 * 256;
    _Float16* wtout_r = p;             p += 256 * 256;
    float* inv_us = (float*)p;         // MU_PAD
    float* inv_rd = inv_us + MU_PAD;   // MR_PAD
    float* inv_ns = inv_rd + MR_PAD;
    float* inv_nd = inv_ns + MR_PAD;
    int* cnt_ur = (int*)(inv_nd + MR_PAD);  // N_REST
    int* cnt_ru = cnt_ur + N_REST;          // N_USER
    int* cnt_rr = cnt_ru + N_USER;          // N_REST
    int* cnt_ns = cnt_rr + N_REST;          // N_REST
    int* ptr_ur = cnt_ns + N_REST;          // N_REST+1
    int* ptr_ru = ptr_ur + N_REST + 4;      // N_USER+1 (pad for int4 alignment)
    int* ptr_rr = ptr_ru + N_USER + 4;      // N_REST+1
    int* csr_ur = ptr_rr + N_REST + 4;      // E_REV
    int* csr_ru = csr_ur + E_REV;           // E_REV
    int* csr_rr = csr_ru + E_REV;           // E_NEAR
    int* slot_ur = csr_rr + E_NEAR;         // E_REV
    int* slot_ru = slot_ur + E_REV;         // E_REV
    int* slot_rr = slot_ru + E_REV;         // E_NEAR

    CFArgs cf;
    cf.rsrc = rev_src; cf.rdst = rev_dst; cf.nsrc = near_src; cf.ndst = near_dst;
    cf.cnt_ur = cnt_ur; cf.cnt_ru = cnt_ru; cf.cnt_rr = cnt_rr; cf.cnt_ns = cnt_ns;
    cf.slot_ur = slot_ur; cf.slot_ru = slot_ru; cf.slot_rr = slot_rr;
    cf.ptr_ur = ptr_ur; cf.ptr_ru = ptr_ru; cf.ptr_rr = ptr_rr;
    cf.csr_ur = csr_ur; cf.csr_ru = csr_ru; cf.csr_rr = csr_rr;

    hipMemsetAsync(cnt_ur, 0, (size_t)(3 * N_REST + N_USER) * sizeof(int), stream);

    // ---- weight prep ----
    WJobs jb;
    jb.w[0] = Win_user; jb.wt[0] = wtin_u; jb.K[0] = 512;
    jb.w[1] = Win_rest; jb.wt[1] = wtin_r; jb.K[1] = 512;
    jb.w[2] = W1_ur; jb.wt[2] = wt1ur; jb.K[2] = 256;
    jb.w[3] = W1_ru; jb.wt[3] = wt1ru; jb.K[3] = 256;
    jb.w[4] = W1_rr; jb.wt[4] = wt1rr; jb.K[4] = 256;
    jb.w[5] = W2_ur; jb.wt[5] = wt2ur; jb.K[5] = 256;
    jb.w[6] = W2_ru; jb.wt[6] = wt2ru; jb.K[6] = 256;
    jb.w[7] = W2_rr; jb.wt[7] = wt2rr; jb.K[7] = 256;
    jb.w[8] = Wout_user; jb.wt[8] = wtout_u; jb.K[8] = 256;
    jb.w[9] = Wout_rest; jb.wt[9] = wtout_r; jb.K[9] = 256;
    wprep<<<dim3(512, 10), 256, 0, stream>>>(jb);

    const int MBU = MU_PAD / 128, MBR = MR_PAD / 128;
    const int G_IN = MBU + MBR;            // 548
    const int G_L  = MBU + 2 * MBR;        // 705

    // ---- input projections (K=512, fp32 A) + CSR count fused ----
    {
        GJobs g;
        g.A[0] = x_user; g.Bt[0] = wtin_u; g.C[0] = h_u; g.S[0] = nullptr; g.MB[0] = MBU; g.Mreal[0] = N_USER;
        g.A[1] = x_rest; g.Bt[1] = wtin_r; g.C[1] = h_r; g.S[1] = nullptr; g.MB[1] = MBR; g.Mreal[1] = N_REST;
        g.A[2] = x_user; g.Bt[2] = wtin_u; g.C[2] = h_u; g.S[2] = nullptr; g.MB[2] = 0;   g.Mreal[2] = N_USER;
        k_gemm<512, true, false, true, 1, 2><<<G_IN, 512, 0, stream>>>(g, cf, ceil_div(E_TOT, G_IN));
    }

    // ---- inv degrees + 3 scans in one launch ----
    ScanJobs sj;
    sj.cnt[0] = cnt_ur; sj.ptr[0] = ptr_ur; sj.n[0] = N_REST;
    sj.cnt[1] = cnt_ru; sj.ptr[1] = ptr_ru; sj.n[1] = N_USER;
    sj.cnt[2] = cnt_rr; sj.ptr[2] = ptr_rr; sj.n[2] = N_REST;
    invscan<<<3 + ceil_div(N_USER, 1024), 1024, 0, stream>>>(sj, cnt_ru, cnt_ur, cnt_ns, cnt_rr,
                                                             inv_us, inv_rd, inv_ns, inv_nd);

    // ---- layer 1 GEMM + CSR fill fused; then aggregation ----
    {
        GJobs g;
        g.A[0] = h_u; g.Bt[0] = wt1ur; g.C[0] = hwu; g.S[0] = inv_us; g.MB[0] = MBU; g.Mreal[0] = N_USER;
        g.A[1] = h_r; g.Bt[1] = wt1rr; g.C[1] = hwa; g.S[1] = inv_ns; g.MB[1] = MBR; g.Mreal[1] = N_REST;
        g.A[2] = h_r; g.Bt[2] = wt1ru; g.C[2] = hwb; g.S[2] = inv_rd; g.MB[2] = MBR; g.Mreal[2] = N_REST;
        k_gemm<256, false, true, true, 2, 4><<<G_L, 512, 0, stream>>>(g, cf, ceil_div(E_TOT, G_L));
    }
    agg_all<<<ceil_div((N_REST + N_USER) * 64, 256), 256, 0, stream>>>(
        ptr_ur, csr_ur, hwu, ptr_rr, csr_rr, hwa, ptr_ru, csr_ru, hwb,
        inv_rd, inv_nd, inv_us, b1_ur, b1_rr, b1_ru, h_r, h_u);

    // ---- layer 2 ----
    {
        GJobs g;
        g.A[0] = h_u; g.Bt[0] = wt2ur; g.C[0] = hwu; g.S[0] = inv_us; g.MB[0] = MBU; g.Mreal[0] = N_USER;
        g.A[1] = h_r; g.Bt[1] = wt2rr; g.C[1] = hwa; g.S[1] = inv_ns; g.MB[1] = MBR; g.Mreal[1] = N_REST;
        g.A[2] = h_r; g.Bt[2] = wt2ru; g.C[2] = hwb; g.S[2] = inv_rd; g.MB[2] = MBR; g.Mreal[2] = N_REST;
        k_gemm<256, false, true, true, 0, 4><<<G_L, 512, 0, stream>>>(g, cf, 0);
    }
    agg_all<<<ceil_div((N_REST + N_USER) * 64, 256), 256, 0, stream>>>(
        ptr_ur, csr_ur, hwu, ptr_rr, csr_rr, hwa, ptr_ru, csr_ru, hwb,
        inv_rd, inv_nd, inv_us, b2_ur, b2_rr, b2_ru, h_r, h_u);

    // ---- output projections (fp32 out, M-guarded) ----
    float* out_user = (float*)d_out;
    float* out_rest = out_user + (size_t)N_USER * HID;
    {
        GJobs g;
        g.A[0] = h_u; g.Bt[0] = wtout_u; g.C[0] = out_user; g.S[0] = nullptr; g.MB[0] = MBU; g.Mreal[0] = N_USER;
        g.A[1] = h_r; g.Bt[1] = wtout_r; g.C[1] = out_rest; g.S[1] = nullptr; g.MB[1] = MBR; g.Mreal[1] = N_REST;
        g.A[2] = h_u; g.Bt[2] = wtout_u; g.C[2] = out_user; g.S[2] = nullptr; g.MB[2] = 0;   g.Mreal[2] = N_USER;
        k_gemm<256, false, false, false, 0, 4><<<G_IN, 512, 0, stream>>>(g, cf, 0);
    }
}

// Round 6
// 568.542 us; speedup vs baseline: 1.2519x; 1.2519x over previous
//
#include <hip/hip_runtime.h>

#define N_USER 50000
#define N_REST 20000
#define D_IN   512
#define HID    256
#define E_REV  500000
#define E_NEAR 250000
#define E_TOT  (E_REV + E_NEAR)
#define MU_PAD 50048   // ceil(50000/128)*128
#define MR_PAD 20096   // ceil(20000/128)*128
#define ECH    4096    // edges per fused edge-chunk block

static inline int ceil_div(int a, int b) { return (a + b - 1) / b; }

typedef _Float16 f16x8 __attribute__((ext_vector_type(8)));
typedef _Float16 f16x4 __attribute__((ext_vector_type(4)));
typedef float    f32x4 __attribute__((ext_vector_type(4)));

typedef const __attribute__((address_space(1))) void* gaddr_t;
typedef __attribute__((address_space(3))) void*       saddr_t;

// ---------------------------------------------------------------------------
// CSR-build edge bodies, fused as interleaved chunk-blocks in GEMM launches.
// ---------------------------------------------------------------------------
struct CFArgs {
    const int *rsrc, *rdst, *nsrc, *ndst;
    int *cnt_ur, *cnt_ru, *cnt_rr, *cnt_ns;
    int *slot_ur, *slot_ru, *slot_rr;
    const int *ptr_ur, *ptr_ru, *ptr_rr;
    int *csr_ur, *csr_ru, *csr_rr;
};

__device__ __forceinline__ void count_edge(const CFArgs& a, int e) {
    if (e < E_REV) {
        int s = a.rsrc[e], d = a.rdst[e];
        a.slot_ur[e] = atomicAdd(&a.cnt_ur[d], 1);
        a.slot_ru[e] = atomicAdd(&a.cnt_ru[s], 1);
    } else {
        int e2 = e - E_REV;
        int s = a.nsrc[e2], d = a.ndst[e2];
        atomicAdd(&a.cnt_ns[s], 1);
        a.slot_rr[e2] = atomicAdd(&a.cnt_rr[d], 1);
    }
}

__device__ __forceinline__ void fill_edge(const CFArgs& a, int e) {
    if (e < E_REV) {
        int s = a.rsrc[e], d = a.rdst[e];
        a.csr_ur[a.ptr_ur[d] + a.slot_ur[e]] = s;
        a.csr_ru[a.ptr_ru[s] + a.slot_ru[e]] = d;
    } else {
        int e2 = e - E_REV;
        a.csr_rr[a.ptr_rr[a.ndst[e2]] + a.slot_rr[e2]] = a.nsrc[e2];
    }
}

// ---------------------------------------------------------------------------
// Batched f16 MFMA GEMM body (r3-verified): C[M,256] = A[M,K] @ Bt[256,K]^T
// BM=128, BN=256, BK=32; 8 waves (512 thr). Double-buffered LDS, counted
// vmcnt (never 0 in steady state), XOR slot swizzle (bank-conflict-free).
// ---------------------------------------------------------------------------
struct GJobs {
    const void* A[3];
    const _Float16* Bt[3];
    void* C[3];
    const float* S[3];
    int MB[3];
    int Mreal[3];
};

template<int KT, bool AFP32, bool SCALE, bool OUT16>
__device__ __forceinline__ void gemm_body(const GJobs& jb, int z, int bx) {
    __shared__ _Float16 As[2][128][32];
    __shared__ _Float16 Bs[2][256][32];

    const int M = jb.Mreal[z];
    const _Float16* __restrict__ Bt = jb.Bt[z];
    const float* __restrict__ S = jb.S[z];
    void* __restrict__ Cout = jb.C[z];

    const int tid  = threadIdx.x;
    const int wave = tid >> 6, lane = tid & 63;
    const int bm = bx * 128;

    const int srow  = lane >> 2;
    const int sslot = lane & 3;
    const int sswz  = sslot ^ ((lane >> 3) & 3);   // = slot ^ ((row>>1)&3)

    const _Float16* Bg0 = Bt + (size_t)(wave * 32 + srow) * KT + sswz * 8;
    const _Float16* Bg1 = Bg0 + (size_t)16 * KT;

    const float*    Af = nullptr;
    const _Float16* Ah = nullptr;
    {
        int wr = bm + wave * 16 + srow;
        if (AFP32) {
            int r = wr < M ? wr : (M - 1);         // x buffers are NOT padded
            Af = (const float*)jb.A[z] + (size_t)r * KT + sslot * 8;
        } else {
            Ah = (const _Float16*)jb.A[z] + (size_t)wr * KT + sswz * 8;
        }
    }

    f32x4 acc[4][4];
#pragma unroll
    for (int i = 0; i < 4; i++)
#pragma unroll
        for (int j = 0; j < 4; j++) acc[i][j] = (f32x4){0.f, 0.f, 0.f, 0.f};

    const int fr = lane & 15;
    const int q  = lane >> 4;
    const int rslot = (fr >> 1) & 3;
    const int wm = wave >> 2, wn = wave & 3;

    auto stageB = [&](int b, int k0) {
        __builtin_amdgcn_global_load_lds((gaddr_t)(Bg0 + k0), (saddr_t)&Bs[b][wave * 32][0], 16, 0, 0);
        __builtin_amdgcn_global_load_lds((gaddr_t)(Bg1 + k0), (saddr_t)&Bs[b][wave * 32 + 16][0], 16, 0, 0);
    };
    auto stageA16 = [&](int b, int k0) {
        __builtin_amdgcn_global_load_lds((gaddr_t)(Ah + k0), (saddr_t)&As[b][wave * 16][0], 16, 0, 0);
    };
    auto writeA32 = [&](int b, float4 a0, float4 a1) {
        f16x8 h = {(_Float16)a0.x, (_Float16)a0.y, (_Float16)a0.z, (_Float16)a0.w,
                   (_Float16)a1.x, (_Float16)a1.y, (_Float16)a1.z, (_Float16)a1.w};
        *(f16x8*)((char*)&As[b][wave * 16 + srow][0] + sswz * 16) = h;
    };

    constexpr int NT = KT >> 5;

    // prologue: tile 0 -> buf 0
    if (AFP32) {
        float4 a0 = *(const float4*)(Af);
        float4 a1 = *(const float4*)(Af + 4);
        stageB(0, 0);
        writeA32(0, a0, a1);
        asm volatile("s_waitcnt lgkmcnt(0)" ::: "memory");
    } else {
        stageB(0, 0);
        stageA16(0, 0);
    }

#pragma unroll 2
    for (int t = 0; t < NT; ++t) {
        const int b = t & 1;
        const bool pf = (t + 1 < NT);
        const int kn = (t + 1) << 5;
        float4 a0, a1;
        if (pf) {
            if (AFP32) {
                a0 = *(const float4*)(Af + kn);
                a1 = *(const float4*)(Af + kn + 4);
                stageB(b ^ 1, kn);
            } else {
                stageB(b ^ 1, kn);
                stageA16(b ^ 1, kn);
            }
        }
        if (pf) {
            if (AFP32) asm volatile("s_waitcnt vmcnt(4)" ::: "memory");
            else       asm volatile("s_waitcnt vmcnt(3)" ::: "memory");
        } else {
            asm volatile("s_waitcnt vmcnt(0)" ::: "memory");
        }
        __builtin_amdgcn_s_barrier();
        __builtin_amdgcn_sched_barrier(0);

        f16x8 af[4], bf[4];
#pragma unroll
        for (int i = 0; i < 4; i++)
            af[i] = *(const f16x8*)((const char*)&As[b][wm * 64 + i * 16 + fr][0] + ((q ^ rslot) << 4));
#pragma unroll
        for (int j = 0; j < 4; j++)
            bf[j] = *(const f16x8*)((const char*)&Bs[b][wn * 64 + j * 16 + fr][0] + ((q ^ rslot) << 4));

#pragma unroll
        for (int i = 0; i < 4; i++)
#pragma unroll
            for (int j = 0; j < 4; j++)
                acc[i][j] = __builtin_amdgcn_mfma_f32_16x16x32_f16(af[i], bf[j], acc[i][j], 0, 0, 0);

        if (pf && AFP32) {
            writeA32(b ^ 1, a0, a1);
            asm volatile("s_waitcnt lgkmcnt(0)" ::: "memory");
        }
        __builtin_amdgcn_sched_barrier(0);
        __builtin_amdgcn_s_barrier();
    }

#pragma unroll
    for (int i = 0; i < 4; i++) {
        const int row0 = bm + wm * 64 + i * 16 + q * 4;
        float sv[4];
        if (SCALE) {
#pragma unroll
            for (int rr = 0; rr < 4; rr++) sv[rr] = S[row0 + rr];
        }
#pragma unroll
        for (int j = 0; j < 4; j++) {
            const int col = wn * 64 + j * 16 + fr;
#pragma unroll
            for (int rr = 0; rr < 4; rr++) {
                const int gr = row0 + rr;
                float v = acc[i][j][rr];
                if (SCALE) v *= sv[rr];
                if (OUT16) {
                    ((_Float16*)Cout)[(size_t)gr * HID + col] = (_Float16)v;
                } else {
                    if (gr < M) ((float*)Cout)[(size_t)gr * HID + col] = v;
                }
            }
        }
    }
}

// FUSE: 0 = plain; 1 = count chunks interleaved; 2 = fill chunks interleaved.
// Interleave: every P-th block (x%P==P-1, x/P<NE) is an edge-chunk block of
// ECH edges. P = floor((NG+NE)/NE) >= 2 guarantees all NE chunks are mapped.
template<int KT, bool AFP32, bool SCALE, bool OUT16, int FUSE>
__global__ __launch_bounds__(512, 2) void k_gemm(GJobs jb, CFArgs cf, int P, int NE) {
    int x = blockIdx.x;
    int bx;
    if (FUSE != 0) {
        int ec = x / P, r = x - ec * P;
        if (r == P - 1 && ec < NE) {
            int base = ec * ECH;
#pragma unroll
            for (int ii = 0; ii < ECH / 512; ii++) {
                int e = base + ii * 512 + (int)threadIdx.x;
                if (e < E_TOT) {
                    if (FUSE == 1) count_edge(cf, e);
                    else           fill_edge(cf, e);
                }
            }
            return;
        }
        bx = x - (ec < NE ? ec : NE);
    } else {
        bx = x;
    }
    int z = 0;
    if (bx >= jb.MB[0]) {
        bx -= jb.MB[0]; z = 1;
        if (bx >= jb.MB[1]) { bx -= jb.MB[1]; z = 2; }
    }
    gemm_body<KT, AFP32, SCALE, OUT16>(jb, z, bx);
}

// Weight prep: W[K][256] fp32 -> Wt[256][K] f16 (batched over 10 matrices)
struct WJobs { const float* w[10]; _Float16* wt[10]; int K[10]; };
__global__ void wprep(WJobs jb) {
    int m = blockIdx.y;
    const float* w = jb.w[m];
    _Float16* wt = jb.wt[m];
    int K = jb.K[m];
    int o = blockIdx.x * 256 + threadIdx.x;
    if (o >= K * 256) return;
    int n = (K == 512) ? (o >> 9) : (o >> 8);
    int k = o & (K - 1);
    wt[o] = (_Float16)w[(size_t)k * 256 + n];
}

__device__ __forceinline__ float inv_deg(int c, float add) {
    float d = (float)c + add;
    return (d > 0.f) ? rsqrtf(d) : 0.f;
}

// Fused: blocks 0-2 run the 3 exclusive scans; blocks 3+ compute inv degrees.
struct ScanJobs { const int* cnt[3]; int* ptr[3]; int n[3]; };
__global__ __launch_bounds__(1024) void invscan(ScanJobs jb,
        const int* __restrict__ cnt_ru, const int* __restrict__ cnt_ur,
        const int* __restrict__ cnt_ns, const int* __restrict__ cnt_rr,
        float* __restrict__ inv_us, float* __restrict__ inv_rd,
        float* __restrict__ inv_ns, float* __restrict__ inv_nd) {
    if (blockIdx.x >= 3) {
        int i = (blockIdx.x - 3) * 1024 + threadIdx.x;
        if (i < N_USER) inv_us[i] = inv_deg(cnt_ru[i], 0.f);
        if (i < N_REST) {
            inv_rd[i] = inv_deg(cnt_ur[i], 0.f);
            inv_ns[i] = inv_deg(cnt_ns[i], 1.f);
            inv_nd[i] = inv_deg(cnt_rr[i], 1.f);
        }
        return;
    }
    const int* cnt = jb.cnt[blockIdx.x];
    int* ptr = jb.ptr[blockIdx.x];
    const int n = jb.n[blockIdx.x];          // divisible by 4
    __shared__ int wsum[16];
    __shared__ int carry_s;
    const int tid = threadIdx.x, lane = tid & 63, wid = tid >> 6;
    if (tid == 0) carry_s = 0;
    __syncthreads();
    for (int base = 0; base < n; base += 4096) {
        int i0 = base + tid * 4;
        int4 v = make_int4(0, 0, 0, 0);
        if (i0 < n) v = *(const int4*)&cnt[i0];
        int s = v.x + v.y + v.z + v.w;
        int x = s;
#pragma unroll
        for (int off = 1; off < 64; off <<= 1) {
            int y = __shfl_up(x, off, 64);
            if (lane >= off) x += y;
        }
        if (lane == 63) wsum[wid] = x;
        __syncthreads();
        if (wid == 0 && lane < 16) {
            int w = wsum[lane];
#pragma unroll
            for (int off = 1; off < 16; off <<= 1) {
                int y = __shfl_up(w, off, 16);
                if (lane >= off) w += y;
            }
            wsum[lane] = w;
        }
        __syncthreads();
        int wave_off = (wid > 0) ? wsum[wid - 1] : 0;
        if (i0 < n) {
            int e = carry_s + wave_off + (x - s);
            int4 o = make_int4(e, e + v.x, e + v.x + v.y, e + v.x + v.y + v.z);
            *(int4*)&ptr[i0] = o;
        }
        __syncthreads();
        if (tid == 0) carry_s += wsum[15];
        __syncthreads();
    }
    if (threadIdx.x == 0) ptr[n] = carry_s;
}

// ---------------------------------------------------------------------------
// Fused aggregation (unchanged): at the random-gather fabric floor.
// ---------------------------------------------------------------------------
__device__ __forceinline__ void acc_rows16(const int* __restrict__ csr, int beg, int end,
                                           const _Float16* __restrict__ hw, int c, f32x4& acc) {
    int e = beg;
    for (; e + 3 < end; e += 4) {
        int s0 = csr[e], s1 = csr[e + 1], s2 = csr[e + 2], s3 = csr[e + 3];
        f16x4 v0 = *(const f16x4*)&hw[(size_t)s0 * HID + c];
        f16x4 v1 = *(const f16x4*)&hw[(size_t)s1 * HID + c];
        f16x4 v2 = *(const f16x4*)&hw[(size_t)s2 * HID + c];
        f16x4 v3 = *(const f16x4*)&hw[(size_t)s3 * HID + c];
#pragma unroll
        for (int r = 0; r < 4; r++)
            acc[r] += ((float)v0[r] + (float)v1[r]) + ((float)v2[r] + (float)v3[r]);
    }
    for (; e < end; e++) {
        f16x4 v = *(const f16x4*)&hw[(size_t)csr[e] * HID + c];
#pragma unroll
        for (int r = 0; r < 4; r++) acc[r] += (float)v[r];
    }
}

__global__ __launch_bounds__(256) void agg_all(
    const int* __restrict__ ptr_ur, const int* __restrict__ csr_ur, const _Float16* __restrict__ hwu,
    const int* __restrict__ ptr_rr, const int* __restrict__ csr_rr, const _Float16* __restrict__ hwa,
    const int* __restrict__ ptr_ru, const int* __restrict__ csr_ru, const _Float16* __restrict__ hwb,
    const float* __restrict__ inv_rd, const float* __restrict__ inv_nd, const float* __restrict__ inv_us,
    const float* __restrict__ b_ur, const float* __restrict__ b_rr, const float* __restrict__ b_ru,
    _Float16* __restrict__ out_r, _Float16* __restrict__ out_u) {
    int w = (blockIdx.x * blockDim.x + threadIdx.x) >> 6;
    int c = (threadIdx.x & 63) * 4;

    if (w < N_REST) {
        int row = w;
        f32x4 au = (f32x4){0.f, 0.f, 0.f, 0.f};
        acc_rows16(csr_ur, ptr_ur[row], ptr_ur[row + 1], hwu, c, au);

        f32x4 ar;
        {   // self-loop (hwa pre-scaled by inv_ns)
            f16x4 v = *(const f16x4*)&hwa[(size_t)row * HID + c];
#pragma unroll
            for (int r = 0; r < 4; r++) ar[r] = (float)v[r];
        }
        acc_rows16(csr_rr, ptr_rr[row], ptr_rr[row + 1], hwa, c, ar);

        float sd = inv_rd[row], sn = inv_nd[row];
        f32x4 bu = *(const f32x4*)&b_ur[c];
        f32x4 br = *(const f32x4*)&b_rr[c];
        f16x4 oh;
#pragma unroll
        for (int r = 0; r < 4; r++)
            oh[r] = (_Float16)fmaxf(bu[r] + br[r] + sd * au[r] + sn * ar[r], 0.f);
        *(f16x4*)&out_r[(size_t)row * HID + c] = oh;
    } else {
        int row = w - N_REST;
        if (row >= N_USER) return;
        f32x4 a = (f32x4){0.f, 0.f, 0.f, 0.f};
        acc_rows16(csr_ru, ptr_ru[row], ptr_ru[row + 1], hwb, c, a);

        float su = inv_us[row];
        f32x4 b = *(const f32x4*)&b_ru[c];
        f16x4 oh;
#pragma unroll
        for (int r = 0; r < 4; r++)
            oh[r] = (_Float16)fmaxf(b[r] + su * a[r], 0.f);
        *(f16x4*)&out_u[(size_t)row * HID + c] = oh;
    }
}

// ---------------------------------------------------------------------------
extern "C" void kernel_launch(void* const* d_in, const int* in_sizes, int n_in,
                              void* d_out, int out_size, void* d_ws, size_t ws_size,
                              hipStream_t stream) {
    const float* x_user   = (const float*)d_in[0];
    const float* x_rest   = (const float*)d_in[1];
    const int*   rev_src  = (const int*)d_in[2];
    const int*   rev_dst  = (const int*)d_in[3];
    const int*   near_src = (const int*)d_in[4];
    const int*   near_dst = (const int*)d_in[5];
    const float* Win_user = (const float*)d_in[6];
    const float* Win_rest = (const float*)d_in[7];
    const float* W1_ur = (const float*)d_in[8];  const float* b1_ur = (const float*)d_in[9];
    const float* W1_ru = (const float*)d_in[10]; const float* b1_ru = (const float*)d_in[11];
    const float* W1_rr = (const float*)d_in[12]; const float* b1_rr = (const float*)d_in[13];
    const float* W2_ur = (const float*)d_in[14]; const float* b2_ur = (const float*)d_in[15];
    const float* W2_ru = (const float*)d_in[16]; const float* b2_ru = (const float*)d_in[17];
    const float* W2_rr = (const float*)d_in[18]; const float* b2_rr = (const float*)d_in[19];
    const float* Wout_user = (const float*)d_in[20];
    const float* Wout_rest = (const float*)d_in[21];

    // ---- workspace layout ----
    _Float16* p = (_Float16*)d_ws;
    _Float16* h_u = p;                 p += (size_t)MU_PAD * HID;
    _Float16* h_r = p;                 p += (size_t)MR_PAD * HID;
    _Float16* hwu = p;                 p += (size_t)MU_PAD * HID;
    _Float16* hwa = p;                 p += (size_t)MR_PAD * HID;
    _Float16* hwb = p;                 p += (size_t)MR_PAD * HID;
    _Float16* wtin_u = p;              p += 256 * 512;
    _Float16* wtin_r = p;              p += 256 * 512;
    _Float16* wt1ur = p;               p += 256 * 256;
    _Float16* wt1ru = p;               p += 256 * 256;
    _Float16* wt1rr = p;               p += 256 * 256;
    _Float16* wt2ur = p;               p += 256 * 256;
    _Float16* wt2ru = p;               p += 256 * 256;
    _Float16* wt2rr = p;               p += 256 * 256;
    _Float16* wtout_u = p;             p += 256 * 256;
    _Float16* wtout_r = p;             p += 256 * 256;
    float* inv_us = (float*)p;         // MU_PAD
    float* inv_rd = inv_us + MU_PAD;   // MR_PAD
    float* inv_ns = inv_rd + MR_PAD;
    float* inv_nd = inv_ns + MR_PAD;
    int* cnt_ur = (int*)(inv_nd + MR_PAD);  // N_REST
    int* cnt_ru = cnt_ur + N_REST;          // N_USER
    int* cnt_rr = cnt_ru + N_USER;          // N_REST
    int* cnt_ns = cnt_rr + N_REST;          // N_REST
    int* ptr_ur = cnt_ns + N_REST;          // N_REST+1
    int* ptr_ru = ptr_ur + N_REST + 4;      // N_USER+1 (pad for int4 alignment)
    int* ptr_rr = ptr_ru + N_USER + 4;      // N_REST+1
    int* csr_ur = ptr_rr + N_REST + 4;      // E_REV
    int* csr_ru = csr_ur + E_REV;           // E_REV
    int* csr_rr = csr_ru + E_REV;           // E_NEAR
    int* slot_ur = csr_rr + E_NEAR;         // E_REV
    int* slot_ru = slot_ur + E_REV;         // E_REV
    int* slot_rr = slot_ru + E_REV;         // E_NEAR

    CFArgs cf;
    cf.rsrc = rev_src; cf.rdst = rev_dst; cf.nsrc = near_src; cf.ndst = near_dst;
    cf.cnt_ur = cnt_ur; cf.cnt_ru = cnt_ru; cf.cnt_rr = cnt_rr; cf.cnt_ns = cnt_ns;
    cf.slot_ur = slot_ur; cf.slot_ru = slot_ru; cf.slot_rr = slot_rr;
    cf.ptr_ur = ptr_ur; cf.ptr_ru = ptr_ru; cf.ptr_rr = ptr_rr;
    cf.csr_ur = csr_ur; cf.csr_ru = csr_ru; cf.csr_rr = csr_rr;

    hipMemsetAsync(cnt_ur, 0, (size_t)(3 * N_REST + N_USER) * sizeof(int), stream);

    // ---- weight prep ----
    WJobs jb;
    jb.w[0] = Win_user; jb.wt[0] = wtin_u; jb.K[0] = 512;
    jb.w[1] = Win_rest; jb.wt[1] = wtin_r; jb.K[1] = 512;
    jb.w[2] = W1_ur; jb.wt[2] = wt1ur; jb.K[2] = 256;
    jb.w[3] = W1_ru; jb.wt[3] = wt1ru; jb.K[3] = 256;
    jb.w[4] = W1_rr; jb.wt[4] = wt1rr; jb.K[4] = 256;
    jb.w[5] = W2_ur; jb.wt[5] = wt2ur; jb.K[5] = 256;
    jb.w[6] = W2_ru; jb.wt[6] = wt2ru; jb.K[6] = 256;
    jb.w[7] = W2_rr; jb.wt[7] = wt2rr; jb.K[7] = 256;
    jb.w[8] = Wout_user; jb.wt[8] = wtout_u; jb.K[8] = 256;
    jb.w[9] = Wout_rest; jb.wt[9] = wtout_r; jb.K[9] = 256;
    wprep<<<dim3(512, 10), 256, 0, stream>>>(jb);

    const int MBU = MU_PAD / 128, MBR = MR_PAD / 128;
    const int G_IN = MBU + MBR;            // 548 gemm blocks
    const int G_L  = MBU + 2 * MBR;        // 705 gemm blocks
    const int NE   = ceil_div(E_TOT, ECH); // 184 edge-chunk blocks
    const int P_IN = (G_IN + NE) / NE;     // 3
    const int P_L  = (G_L + NE) / NE;      // 4

    // ---- input projections (K=512, fp32 A) + CSR count interleaved ----
    {
        GJobs g;
        g.A[0] = x_user; g.Bt[0] = wtin_u; g.C[0] = h_u; g.S[0] = nullptr; g.MB[0] = MBU; g.Mreal[0] = N_USER;
        g.A[1] = x_rest; g.Bt[1] = wtin_r; g.C[1] = h_r; g.S[1] = nullptr; g.MB[1] = MBR; g.Mreal[1] = N_REST;
        g.A[2] = x_user; g.Bt[2] = wtin_u; g.C[2] = h_u; g.S[2] = nullptr; g.MB[2] = 0;   g.Mreal[2] = N_USER;
        k_gemm<512, true, false, true, 1><<<G_IN + NE, 512, 0, stream>>>(g, cf, P_IN, NE);
    }

    // ---- inv degrees + 3 scans in one launch ----
    ScanJobs sj;
    sj.cnt[0] = cnt_ur; sj.ptr[0] = ptr_ur; sj.n[0] = N_REST;
    sj.cnt[1] = cnt_ru; sj.ptr[1] = ptr_ru; sj.n[1] = N_USER;
    sj.cnt[2] = cnt_rr; sj.ptr[2] = ptr_rr; sj.n[2] = N_REST;
    invscan<<<3 + ceil_div(N_USER, 1024), 1024, 0, stream>>>(sj, cnt_ru, cnt_ur, cnt_ns, cnt_rr,
                                                             inv_us, inv_rd, inv_ns, inv_nd);

    // ---- layer 1 GEMM + CSR fill interleaved; then aggregation ----
    {
        GJobs g;
        g.A[0] = h_u; g.Bt[0] = wt1ur; g.C[0] = hwu; g.S[0] = inv_us; g.MB[0] = MBU; g.Mreal[0] = N_USER;
        g.A[1] = h_r; g.Bt[1] = wt1rr; g.C[1] = hwa; g.S[1] = inv_ns; g.MB[1] = MBR; g.Mreal[1] = N_REST;
        g.A[2] = h_r; g.Bt[2] = wt1ru; g.C[2] = hwb; g.S[2] = inv_rd; g.MB[2] = MBR; g.Mreal[2] = N_REST;
        k_gemm<256, false, true, true, 2><<<G_L + NE, 512, 0, stream>>>(g, cf, P_L, NE);
    }
    agg_all<<<ceil_div((N_REST + N_USER) * 64, 256), 256, 0, stream>>>(
        ptr_ur, csr_ur, hwu, ptr_rr, csr_rr, hwa, ptr_ru, csr_ru, hwb,
        inv_rd, inv_nd, inv_us, b1_ur, b1_rr, b1_ru, h_r, h_u);

    // ---- layer 2 ----
    {
        GJobs g;
        g.A[0] = h_u; g.Bt[0] = wt2ur; g.C[0] = hwu; g.S[0] = inv_us; g.MB[0] = MBU; g.Mreal[0] = N_USER;
        g.A[1] = h_r; g.Bt[1] = wt2rr; g.C[1] = hwa; g.S[1] = inv_ns; g.MB[1] = MBR; g.Mreal[1] = N_REST;
        g.A[2] = h_r; g.Bt[2] = wt2ru; g.C[2] = hwb; g.S[2] = inv_rd; g.MB[2] = MBR; g.Mreal[2] = N_REST;
        k_gemm<256, false, true, true, 0><<<G_L, 512, 0, stream>>>(g, cf, 1, 0);
    }
    agg_all<<<ceil_div((N_REST + N_USER) * 64, 256), 256, 0, stream>>>(
        ptr_ur, csr_ur, hwu, ptr_rr, csr_rr, hwa, ptr_ru, csr_ru, hwb,
        inv_rd, inv_nd, inv_us, b2_ur, b2_rr, b2_ru, h_r, h_u);

    // ---- output projections (fp32 out, M-guarded) ----
    float* out_user = (float*)d_out;
    float* out_rest = out_user + (size_t)N_USER * HID;
    {
        GJobs g;
        g.A[0] = h_u; g.Bt[0] = wtout_u; g.C[0] = out_user; g.S[0] = nullptr; g.MB[0] = MBU; g.Mreal[0] = N_USER;
        g.A[1] = h_r; g.Bt[1] = wtout_r; g.C[1] = out_rest; g.S[1] = nullptr; g.MB[1] = MBR; g.Mreal[1] = N_REST;
        g.A[2] = h_u; g.Bt[2] = wtout_u; g.C[2] = out_user; g.S[2] = nullptr; g.MB[2] = 0;   g.Mreal[2] = N_USER;
        k_gemm<256, false, false, false, 0><<<G_IN, 512, 0, stream>>>(g, cf, 1, 0);
    }
}